// Round 3
// baseline (235.073 us; speedup 1.0000x reference)
//
#include <hip/hip_runtime.h>

#define F 16
#define BSHIFT 8
#define NPB 256           // nodes per bucket
#define NB 391            // buckets for N=100000
#define CH 4096           // edges per reorder block
#define BCAP 9216         // padded per-bucket edge capacity (mean 8184, sd ~90)
#define QCAP 2432         // per-quarter (64-node) edge capacity (mean 2048, sd ~45)

// ========================= fast path kernels ================================

__global__ void init_cursor_kernel(unsigned* __restrict__ cursor) {
    int i = threadIdx.x;
    if (i < NB) cursor[i * 16] = (unsigned)(i * BCAP);
}

// bucket reorder via rank-trick counting sort. 512 threads, 1 LDS-atomic pass,
// src cached in registers (no re-read). rec = src | (dst&255)<<17
__global__ __launch_bounds__(512) void
reorder_kernel(const int* __restrict__ src, const int* __restrict__ dst,
               unsigned* __restrict__ cursor, unsigned* __restrict__ recs, int E) {
    __shared__ unsigned lsorted[CH];
    __shared__ unsigned short lbkt[CH];
    __shared__ unsigned cnt[NB];       // counts; later reused as global run base
    __shared__ unsigned lstart[NB + 1];
    int t = threadIdx.x, b = blockIdx.x;
    int e0 = b * CH;
    int cnt_e = E - e0; if (cnt_e > CH) cnt_e = CH;

    for (int i = t; i < NB; i += 512) cnt[i] = 0;
    __syncthreads();
    // phase 1: histogram + per-edge (bucket,low,rank) and src kept in registers
    unsigned pk[8], rs[8];
#pragma unroll
    for (int j = 0; j < 8; ++j) {
        int i = t + j * 512;
        pk[j] = 0xFFFFFFFFu;
        if (i < cnt_e) {
            unsigned d = (unsigned)dst[e0 + i];
            rs[j] = (unsigned)src[e0 + i];
            unsigned bk = d >> BSHIFT;
            unsigned r = atomicAdd(&cnt[bk], 1u);
            pk[j] = bk | ((d & 255u) << 9) | (r << 17);   // bk:9 | low:8 | rank:12
        }
    }
    __syncthreads();
    // phase 2: exclusive scan of NB counts by wave 0
    if (t < 64) {
        unsigned run = 0;
        for (int c = 0; c < NB; c += 64) {
            int idx = c + t;
            unsigned v = (idx < NB) ? cnt[idx] : 0u;
            unsigned inc = v;
#pragma unroll
            for (int d = 1; d < 64; d <<= 1) {
                unsigned o = __shfl_up(inc, d, 64);
                if (t >= d) inc += o;
            }
            if (idx < NB) lstart[idx] = run + inc - v;
            run += __shfl(inc, 63, 64);
        }
        if (t == 0) lstart[NB] = (unsigned)cnt_e;
    }
    __syncthreads();
    // phase 3: reserve global run per touched bucket (staggered sweep start to
    // decorrelate cursor-line contention across blocks); cnt[i] becomes base
    {
        int s0 = (int)(((unsigned)b * 101u) % (unsigned)NB);
        for (int q = t; q < NB; q += 512) {
            int i = s0 + q; if (i >= NB) i -= NB;
            unsigned c = cnt[i];
            if (c) cnt[i] = atomicAdd(&cursor[i * 16], c);
        }
    }
    __syncthreads();
    // phase 4: non-atomic LDS scatter from registers
#pragma unroll
    for (int j = 0; j < 8; ++j) {
        int i = t + j * 512;
        if (i < cnt_e) {
            unsigned p = pk[j];
            unsigned bk = p & 0x1FFu;
            unsigned pos = lstart[bk] + (p >> 17);
            lsorted[pos] = rs[j] | (((p >> 9) & 255u) << 17);
            lbkt[pos] = (unsigned short)bk;
        }
    }
    __syncthreads();
    // phase 5: run-contiguous global write-out
    for (int i = t; i < cnt_e; i += 512) {
        unsigned bk = lbkt[i];
        recs[cnt[bk] + ((unsigned)i - lstart[bk])] = lsorted[i];
    }
}

// per-bucket degree histogram -> dinv (local only); fused z = x*dinv
__global__ __launch_bounds__(1024) void
histz_kernel(const unsigned* __restrict__ recs, const unsigned* __restrict__ cursor,
             const float* __restrict__ x, float* __restrict__ z, int n) {
    __shared__ unsigned cnt[NPB];
    __shared__ float ldv[NPB];
    int t = threadIdx.x, b = blockIdx.x;
    int e0 = b * BCAP;
    int used = (int)(cursor[b * 16] - (unsigned)e0);
    if (t < NPB) cnt[t] = 0;
    __syncthreads();
    for (int i = t; i < used; i += 1024)
        atomicAdd(&cnt[recs[e0 + i] >> 17], 1u);
    __syncthreads();
    if (t < NPB) ldv[t] = rsqrtf((float)cnt[t] + 1.0f);
    __syncthreads();
    int node = b * NPB + (t >> 2);
    if (node < n) {
        float4 v = ((const float4*)x)[(size_t)b * 1024 + t];
        float dv = ldv[t >> 2];
        v.x *= dv; v.y *= dv; v.z *= dv; v.w *= dv;
        ((float4*)z)[(size_t)b * 1024 + t] = v;
    }
}

// fused filter + counting-sort + merge-path aggregation + linear epilogue.
// Block = one 64-node quarter of a 256-node bucket. Streams the bucket's recs,
// compacts its quarter to LDS (1 global-stream pass, ballot-aggregated),
// histograms (=> local degree => dinv), rank-scatters to node-sorted LDS list,
// then register-accumulating merge-path over equal chunks with boundary-only
// LDS-atomic flushes. All sort work hides under gather latency (VALUBusy ~8%).
// mode 1: out = relu(dinv*(S@W) + bias) * dinv     (layer-1 -> y)
// mode 2: out = dinv*(S@W) + bias                  (final output)
__global__ __launch_bounds__(256) void
agg_fused_kernel(const float* __restrict__ hin, const unsigned* __restrict__ recs,
                 const unsigned* __restrict__ cursor,
                 const float* __restrict__ W, const float* __restrict__ bias,
                 float* __restrict__ outp, int n, int mode) {
    __shared__ unsigned lraw[QCAP];
    __shared__ unsigned lsort[QCAP];
    __shared__ float acc[64][F + 1];
    __shared__ float Ws[F * F];
    __shared__ unsigned cnt[64];
    __shared__ unsigned ex[64];
    __shared__ float ldv[64];
    __shared__ unsigned nloc_s;
    int t = threadIdx.x, b = blockIdx.x;
    int bucket = b >> 2, q = b & 3;
    int e0 = bucket * BCAP;
    int used = (int)(cursor[bucket * 16] - (unsigned)e0);
    int lane = t & 63;
    Ws[t] = W[t];
    if (t < 64) cnt[t] = 0;
    if (t == 0) nloc_s = 0;
    for (int i = t; i < 64 * (F + 1); i += 256) ((float*)acc)[i] = 0.f;
    __syncthreads();
    // pass A: stream recs, filter to this quarter, compact (1 atomic/wave) + hist
    for (int i = t; i < used; i += 256) {
        unsigned rec = recs[e0 + i];
        unsigned node = rec >> 17;                 // 0..255 within bucket
        bool mine = ((node >> 6) == (unsigned)q);
        unsigned long long m = __ballot(mine);
        if (m) {
            int ldr = __ffsll((long long)m) - 1;
            unsigned base = 0;
            if (lane == ldr) base = atomicAdd(&nloc_s, (unsigned)__popcll(m));
            base = __shfl(base, ldr, 64);
            if (mine) {
                unsigned pre = (unsigned)__popcll(m & ((1ull << lane) - 1ull));
                lraw[base + pre] = rec;
                atomicAdd(&cnt[node & 63u], 1u);
            }
        }
    }
    __syncthreads();
    int nloc = (int)nloc_s;
    // scan of 64 counts (wave 0) + local dinv
    if (t < 64) {
        unsigned c0 = cnt[t];
        unsigned inc = c0;
#pragma unroll
        for (int d = 1; d < 64; d <<= 1) {
            unsigned o = __shfl_up(inc, d, 64);
            if (t >= d) inc += o;
        }
        ex[t] = inc - c0;                 // exclusive start (becomes cursor)
        ldv[t] = rsqrtf((float)c0 + 1.0f);
    }
    __syncthreads();
    // pass B: rank-scatter into node-sorted order
    for (int i = t; i < nloc; i += 256) {
        unsigned rec = lraw[i];
        unsigned pos = atomicAdd(&ex[(rec >> 17) & 63u], 1u);
        lsort[pos] = rec;
    }
    __syncthreads();
    // merge-path segmented aggregation: 64 groups x 4 lanes, equal chunks
    int g = t >> 2, c = t & 3;
    const float4* h4 = (const float4*)hin;
    int chunk = (nloc + 63) >> 6;
    int gs = g * chunk;
    int ge = gs + chunk; if (ge > nloc) ge = nloc;

#define PROC(r, v)                                                        \
    {                                                                     \
        int nd = (int)((r >> 17) & 63u);                                  \
        if (nd != cur) {                                                  \
            float* a = &acc[cur][c * 4];                                  \
            atomicAdd(a + 0, s.x); atomicAdd(a + 1, s.y);                 \
            atomicAdd(a + 2, s.z); atomicAdd(a + 3, s.w);                 \
            s.x = 0.f; s.y = 0.f; s.z = 0.f; s.w = 0.f;                   \
            cur = nd;                                                     \
        }                                                                 \
        s.x += v.x; s.y += v.y; s.z += v.z; s.w += v.w;                   \
    }

    if (gs < ge) {
        int cur = (int)((lsort[gs] >> 17) & 63u);
        float4 s = {0.f, 0.f, 0.f, 0.f};
        int e = gs;
        for (; e + 8 <= ge; e += 8) {
            unsigned r0 = lsort[e + 0], r1 = lsort[e + 1];
            unsigned r2 = lsort[e + 2], r3 = lsort[e + 3];
            unsigned r4 = lsort[e + 4], r5 = lsort[e + 5];
            unsigned r6 = lsort[e + 6], r7 = lsort[e + 7];
            float4 v0 = h4[(size_t)(r0 & 0x1FFFFu) * 4 + c];
            float4 v1 = h4[(size_t)(r1 & 0x1FFFFu) * 4 + c];
            float4 v2 = h4[(size_t)(r2 & 0x1FFFFu) * 4 + c];
            float4 v3 = h4[(size_t)(r3 & 0x1FFFFu) * 4 + c];
            float4 v4 = h4[(size_t)(r4 & 0x1FFFFu) * 4 + c];
            float4 v5 = h4[(size_t)(r5 & 0x1FFFFu) * 4 + c];
            float4 v6 = h4[(size_t)(r6 & 0x1FFFFu) * 4 + c];
            float4 v7 = h4[(size_t)(r7 & 0x1FFFFu) * 4 + c];
            PROC(r0, v0); PROC(r1, v1); PROC(r2, v2); PROC(r3, v3);
            PROC(r4, v4); PROC(r5, v5); PROC(r6, v6); PROC(r7, v7);
        }
        for (; e < ge; ++e) {
            unsigned r0 = lsort[e];
            float4 v0 = h4[(size_t)(r0 & 0x1FFFFu) * 4 + c];
            PROC(r0, v0);
        }
        float* a = &acc[cur][c * 4];
        atomicAdd(a + 0, s.x); atomicAdd(a + 1, s.y);
        atomicAdd(a + 2, s.z); atomicAdd(a + 3, s.w);
    }
#undef PROC
    __syncthreads();
    int node = bucket * NPB + q * 64 + g;
    if (node < n) {   // self contribution (unique 4 floats per thread)
        float4 self = h4[(size_t)node * 4 + c];
        float* ar = &acc[g][c * 4];
        ar[0] += self.x; ar[1] += self.y; ar[2] += self.z; ar[3] += self.w;
    }
    __syncthreads();
    if (node < n) {
        float di = ldv[g];
        float4 o = {0.f, 0.f, 0.f, 0.f};
        int j = c * 4;
#pragma unroll
        for (int k = 0; k < F; ++k) {
            float ak = acc[g][k];
            o.x += ak * Ws[k * F + j + 0];
            o.y += ak * Ws[k * F + j + 1];
            o.z += ak * Ws[k * F + j + 2];
            o.w += ak * Ws[k * F + j + 3];
        }
        float4 bi = ((const float4*)bias)[c];
        o.x = di * o.x + bi.x; o.y = di * o.y + bi.y;
        o.z = di * o.z + bi.z; o.w = di * o.w + bi.w;
        if (mode == 1) {
            o.x = fmaxf(o.x, 0.f) * di; o.y = fmaxf(o.y, 0.f) * di;
            o.z = fmaxf(o.z, 0.f) * di; o.w = fmaxf(o.w, 0.f) * di;
        }
        ((float4*)outp)[(size_t)node * 4 + c] = o;
    }
}

// ========================= fallback (R1) kernels ============================

__global__ void deg_kernel(const int* __restrict__ dst, float* __restrict__ deg, int E) {
    int e = blockIdx.x * blockDim.x + threadIdx.x;
    if (e < E) atomicAdd(&deg[dst[e]], 1.0f);
}
__global__ void dinv_kernel(float* __restrict__ deg, int n) {
    int i = blockIdx.x * blockDim.x + threadIdx.x;
    if (i < n) deg[i] = rsqrtf(deg[i] + 1.0f);
}
__global__ void linear2_kernel(const float* __restrict__ in, const float* __restrict__ acc,
                               const float* __restrict__ dinv, const float* __restrict__ W,
                               const float* __restrict__ bias, float* __restrict__ out,
                               int n, int mode) {
    __shared__ float Ws[F * F];
    __shared__ float As[16][F + 1];
    int t = threadIdx.x;
    Ws[t] = W[t];
    int nb = t >> 4, j = t & 15;
    int i = blockIdx.x * 16 + nb;
    float di = 0.f, v = 0.f;
    if (i < n) {
        di = dinv[i]; v = in[i * F + j];
        if (mode) { v = di * (acc[i * F + j] + v) + bias[j]; v = fmaxf(v, 0.f); }
    }
    As[nb][j] = v;
    __syncthreads();
    if (i < n) {
        float s = 0.f;
#pragma unroll
        for (int k = 0; k < F; ++k) s += As[nb][k] * Ws[k * F + j];
        out[i * F + j] = s * di;
    }
}
__global__ void scatter_kernel(const int* __restrict__ src, const int* __restrict__ dst,
                               const float* __restrict__ h, float* __restrict__ acc, int E) {
    int t = blockIdx.x * blockDim.x + threadIdx.x;
    int e = t >> 4, j = t & 15;
    if (e < E) atomicAdd(&acc[dst[e] * F + j], h[src[e] * F + j]);
}
__global__ void out_kernel(const float* __restrict__ acc, const float* __restrict__ h,
                           const float* __restrict__ dinv, const float* __restrict__ bias,
                           float* __restrict__ out, int n) {
    int t = blockIdx.x * blockDim.x + threadIdx.x;
    if (t < n * F) {
        int i = t >> 4, j = t & 15;
        out[t] = dinv[i] * (acc[t] + h[t]) + bias[j];
    }
}

// ========================= launch ===========================================

extern "C" void kernel_launch(void* const* d_in, const int* in_sizes, int n_in,
                              void* d_out, int out_size, void* d_ws, size_t ws_size,
                              hipStream_t stream) {
    const float* x  = (const float*)d_in[0];
    const int*   ei = (const int*)d_in[1];
    const float* W1 = (const float*)d_in[2];
    const float* b1 = (const float*)d_in[3];
    const float* W2 = (const float*)d_in[4];
    const float* b2 = (const float*)d_in[5];
    float* outp = (float*)d_out;

    const int N = in_sizes[0] / F;
    const int E = in_sizes[1] / 2;
    const int* src = ei;
    const int* dst = ei + E;

    const int nb_rt = (N + NPB - 1) >> BSHIFT;
    const size_t RC = (size_t)NB * BCAP;           // 3,603,456 entries
    // ws layout (4B units): z[16N] | y[16N] | recs[RC] | cursor[16*NB]
    size_t need = sizeof(unsigned) * ((size_t)N * 32 + RC + 16 * NB);

    if (nb_rt == NB && E <= CH * 65535 && ws_size >= need) {
        float* z = (float*)d_ws;
        float* y = z + (size_t)F * N;
        unsigned* recs = (unsigned*)(y + (size_t)F * N);
        unsigned* cursor = recs + RC;

        init_cursor_kernel<<<1, 512, 0, stream>>>(cursor);
        reorder_kernel<<<(E + CH - 1) / CH, 512, 0, stream>>>(src, dst, cursor, recs, E);
        histz_kernel<<<NB, 1024, 0, stream>>>(recs, cursor, x, z, N);
        agg_fused_kernel<<<NB * 4, 256, 0, stream>>>(z, recs, cursor, W1, b1, y, N, 1);
        agg_fused_kernel<<<NB * 4, 256, 0, stream>>>(y, recs, cursor, W2, b2, outp, N, 2);
    } else {
        // R1 fallback: atomic scatter path (13.2MB ws)
        float* dinv = (float*)d_ws;
        float* h = dinv + N;
        float* acc = h + (size_t)F * N;
        hipMemsetAsync(dinv, 0, (size_t)N * sizeof(float), stream);
        hipMemsetAsync(acc, 0, (size_t)F * N * sizeof(float), stream);
        deg_kernel<<<(E + 255) / 256, 256, 0, stream>>>(dst, dinv, E);
        dinv_kernel<<<(N + 255) / 256, 256, 0, stream>>>(dinv, N);
        linear2_kernel<<<(N + 15) / 16, 256, 0, stream>>>(x, nullptr, dinv, W1, nullptr, h, N, 0);
        scatter_kernel<<<((size_t)E * F + 255) / 256, 256, 0, stream>>>(src, dst, h, acc, E);
        linear2_kernel<<<(N + 15) / 16, 256, 0, stream>>>(h, acc, dinv, W2, b1, h, N, 1);
        hipMemsetAsync(acc, 0, (size_t)F * N * sizeof(float), stream);
        scatter_kernel<<<((size_t)E * F + 255) / 256, 256, 0, stream>>>(src, dst, h, acc, E);
        out_kernel<<<((size_t)N * F + 255) / 256, 256, 0, stream>>>(acc, h, dinv, b2, outp, N);
    }
}

// Round 4
// 205.058 us; speedup vs baseline: 1.1464x; 1.1464x over previous
//
#include <hip/hip_runtime.h>

#define F 16
#define BSHIFT 8
#define NPB 256           // nodes per bucket
#define NB 391            // buckets for N=100000
#define CH 4096           // edges per reorder block
#define BCAP 9216         // padded per-bucket edge capacity (mean 8184, sd ~90)

// ========================= fast path kernels ================================

__global__ void init_cursor_kernel(unsigned* __restrict__ cursor) {
    int i = threadIdx.x;
    if (i < NB) cursor[i * 16] = (unsigned)(i * BCAP);
}

// bucket reorder via rank-trick counting sort. 512 threads, 1 LDS-atomic pass,
// src cached in registers (no re-read). rec = src | (dst&255)<<17
__global__ __launch_bounds__(512) void
reorder_kernel(const int* __restrict__ src, const int* __restrict__ dst,
               unsigned* __restrict__ cursor, unsigned* __restrict__ recs, int E) {
    __shared__ unsigned lsorted[CH];
    __shared__ unsigned short lbkt[CH];
    __shared__ unsigned cnt[NB];       // counts; later reused as global run base
    __shared__ unsigned lstart[NB + 1];
    int t = threadIdx.x, b = blockIdx.x;
    int e0 = b * CH;
    int cnt_e = E - e0; if (cnt_e > CH) cnt_e = CH;

    for (int i = t; i < NB; i += 512) cnt[i] = 0;
    __syncthreads();
    // phase 1: histogram + per-edge (bucket,low,rank) and src kept in registers
    unsigned pk[8], rs[8];
#pragma unroll
    for (int j = 0; j < 8; ++j) {
        int i = t + j * 512;
        pk[j] = 0xFFFFFFFFu;
        if (i < cnt_e) {
            unsigned d = (unsigned)dst[e0 + i];
            rs[j] = (unsigned)src[e0 + i];
            unsigned bk = d >> BSHIFT;
            unsigned r = atomicAdd(&cnt[bk], 1u);
            pk[j] = bk | ((d & 255u) << 9) | (r << 17);   // bk:9 | low:8 | rank:12
        }
    }
    __syncthreads();
    // phase 2: exclusive scan of NB counts by wave 0
    if (t < 64) {
        unsigned run = 0;
        for (int c = 0; c < NB; c += 64) {
            int idx = c + t;
            unsigned v = (idx < NB) ? cnt[idx] : 0u;
            unsigned inc = v;
#pragma unroll
            for (int d = 1; d < 64; d <<= 1) {
                unsigned o = __shfl_up(inc, d, 64);
                if (t >= d) inc += o;
            }
            if (idx < NB) lstart[idx] = run + inc - v;
            run += __shfl(inc, 63, 64);
        }
        if (t == 0) lstart[NB] = (unsigned)cnt_e;
    }
    __syncthreads();
    // phase 3: reserve global run per touched bucket (staggered sweep start to
    // decorrelate cursor-line contention across blocks); cnt[i] becomes base
    {
        int s0 = (int)(((unsigned)b * 101u) % (unsigned)NB);
        for (int q = t; q < NB; q += 512) {
            int i = s0 + q; if (i >= NB) i -= NB;
            unsigned c = cnt[i];
            if (c) cnt[i] = atomicAdd(&cursor[i * 16], c);
        }
    }
    __syncthreads();
    // phase 4: non-atomic LDS scatter from registers
#pragma unroll
    for (int j = 0; j < 8; ++j) {
        int i = t + j * 512;
        if (i < cnt_e) {
            unsigned p = pk[j];
            unsigned bk = p & 0x1FFu;
            unsigned pos = lstart[bk] + (p >> 17);
            lsorted[pos] = rs[j] | (((p >> 9) & 255u) << 17);
            lbkt[pos] = (unsigned short)bk;
        }
    }
    __syncthreads();
    // phase 5: run-contiguous global write-out
    for (int i = t; i < cnt_e; i += 512) {
        unsigned bk = lbkt[i];
        recs[cnt[bk] + ((unsigned)i - lstart[bk])] = lsorted[i];
    }
}

// per-bucket (src-half, node) sort via rank-trick, 512 bins. Emits split CSR
// (noffA/nendA for src<NH, noffB/nendB for src>=NH), dinv, sorted srcs (node id
// kept in bits [17:25)), and fused z = x*dinv.
__global__ __launch_bounds__(1024) void
sort2_kernel(const unsigned* __restrict__ recs, const unsigned* __restrict__ cursor,
             unsigned* __restrict__ srcs,
             int* __restrict__ noffA, int* __restrict__ nendA,
             int* __restrict__ noffB, int* __restrict__ nendB,
             float* __restrict__ dinv, const float* __restrict__ x,
             float* __restrict__ z, int n) {
    __shared__ unsigned lsort[BCAP];
    __shared__ unsigned cnt[2 * NPB];
    __shared__ unsigned ex[2 * NPB];
    __shared__ float ldv[NPB];
    __shared__ unsigned wtot[8];
    int t = threadIdx.x, b = blockIdx.x;
    int e0 = b * BCAP;
    int used = (int)(cursor[b * 16] - (unsigned)e0);
    unsigned NH = ((unsigned)n + 1u) >> 1;
    if (t < 2 * NPB) cnt[t] = 0;
    __syncthreads();
    // phase 1: per-(half,node) histogram + rank; full record kept in registers
    unsigned pk[9], rsr[9];
#pragma unroll
    for (int j = 0; j < 9; ++j) {
        int i = t + j * 1024;
        pk[j] = 0xFFFFFFFFu;
        if (i < used) {
            unsigned rec = recs[e0 + i];
            unsigned node = rec >> 17;
            unsigned half = ((rec & 0x1FFFFu) >= NH) ? 1u : 0u;
            unsigned bin = (half << 8) | node;
            rsr[j] = rec;                      // keep src | node<<17
            unsigned r = atomicAdd(&cnt[bin], 1u);
            pk[j] = bin | (r << 9);
        }
    }
    __syncthreads();
    // phase 2: 512-entry exclusive scan (8 waves) + split-CSR emit
    {
        unsigned c = 0, inc = 0;
        int lane = t & 63, w = t >> 6;
        if (t < 2 * NPB) {
            c = cnt[t];
            inc = c;
#pragma unroll
            for (int d = 1; d < 64; d <<= 1) {
                unsigned o = __shfl_up(inc, d, 64);
                if (lane >= d) inc += o;
            }
            if (lane == 63) wtot[w] = inc;
        }
        __syncthreads();
        if (t < 2 * NPB) {
            unsigned wbase = 0;
            for (int i = 0; i < w; ++i) wbase += wtot[i];
            unsigned e = wbase + inc - c;
            ex[t] = e;
            int node = t & 255, half = t >> 8;
            int gnode = b * NPB + node;
            if (gnode < n) {
                if (half == 0) { noffA[gnode] = e0 + (int)e; nendA[gnode] = e0 + (int)(e + c); }
                else           { noffB[gnode] = e0 + (int)e; nendB[gnode] = e0 + (int)(e + c); }
            }
        }
        __syncthreads();
    }
    if (t < NPB) {
        unsigned ctot = cnt[t] + cnt[NPB + t];
        float dv = rsqrtf((float)ctot + 1.0f);
        ldv[t] = dv;
        int gnode = b * NPB + t;
        if (gnode < n) dinv[gnode] = dv;
    }
    __syncthreads();
    // phase 3: non-atomic LDS scatter from registers
#pragma unroll
    for (int j = 0; j < 9; ++j) {
        int i = t + j * 1024;
        if (i < used) {
            unsigned p = pk[j];
            lsort[ex[p & 511u] + (p >> 9)] = rsr[j];
        }
    }
    __syncthreads();
    // phase 4: coalesced write-out
    for (int i = t; i < used; i += 1024) srcs[e0 + i] = lsort[i];
    // phase 5 (fused): z = x * dinv for this block's 256 nodes (1 float4/thread)
    {
        int node = b * NPB + (t >> 2);
        if (node < n) {
            float4 v = ((const float4*)x)[(size_t)b * 1024 + t];
            float dv = ldv[t >> 2];
            v.x *= dv; v.y *= dv; v.z *= dv; v.w *= dv;
            ((float4*)z)[(size_t)b * 1024 + t] = v;
        }
    }
}

// two-phase merge-path segmented CSR aggregation — 64 nodes/block, 256 threads.
// Pass A covers edges with src < NH (gather table = lower 3.2MB of hin, fits
// per-XCD L2); pass B covers src >= NH. Blocks are all co-resident so phases
// align across the GPU. Register accumulation, LDS-atomic flush only at
// segment boundaries.
// mode 1: out = relu(dinv*(S@W) + bias) * dinv     (layer-1 -> y)
// mode 2: out = dinv*(S@W) + bias                  (final output)
__global__ __launch_bounds__(256) void
agg_bal_kernel(const float* __restrict__ hin, const unsigned* __restrict__ srcs,
               const int* __restrict__ noffA, const int* __restrict__ nendA,
               const int* __restrict__ noffB, const int* __restrict__ nendB,
               const float* __restrict__ dinv,
               const float* __restrict__ W, const float* __restrict__ bias,
               float* __restrict__ outp, int n, int mode) {
    __shared__ float acc[64][F + 1];
    __shared__ float Ws[F * F];
    int t = threadIdx.x, b = blockIdx.x;
    int g = t >> 2, c = t & 3;          // 64 groups of 4 lanes (float4 columns)
    Ws[t] = W[t];
    for (int i = t; i < 64 * (F + 1); i += 256) ((float*)acc)[i] = 0.f;
    __syncthreads();
    int nfirst = b * 64;
    int nlast = nfirst + 63; if (nlast > n - 1) nlast = n - 1;
    int rs0 = noffA[nfirst], re0 = nendA[nlast];
    int rs1 = noffB[nfirst], re1 = nendB[nlast];
    const float4* h4 = (const float4*)hin;

#define PROC(r, v)                                                        \
    {                                                                     \
        int nd = (int)((r >> 17) & 63u);                                  \
        if (nd != cur) {                                                  \
            float* a = &acc[cur][c * 4];                                  \
            atomicAdd(a + 0, s.x); atomicAdd(a + 1, s.y);                 \
            atomicAdd(a + 2, s.z); atomicAdd(a + 3, s.w);                 \
            s.x = 0.f; s.y = 0.f; s.z = 0.f; s.w = 0.f;                   \
            cur = nd;                                                     \
        }                                                                 \
        s.x += v.x; s.y += v.y; s.z += v.z; s.w += v.w;                   \
    }

#pragma unroll 1
    for (int p = 0; p < 2; ++p) {
        int S = p ? rs1 : rs0;
        int Eend = p ? re1 : re0;
        int T = Eend - S;
        int chunk = (T + 63) >> 6;
        int gs = S + g * chunk;
        int ge = gs + chunk; if (ge > Eend) ge = Eend;
        if (gs < ge) {
            int cur = (int)((srcs[gs] >> 17) & 63u);
            float4 s = {0.f, 0.f, 0.f, 0.f};
            int e = gs;
            for (; e + 4 <= ge; e += 4) {
                unsigned r0 = srcs[e], r1 = srcs[e + 1], r2 = srcs[e + 2], r3 = srcs[e + 3];
                float4 v0 = h4[(size_t)(r0 & 0x1FFFFu) * 4 + c];
                float4 v1 = h4[(size_t)(r1 & 0x1FFFFu) * 4 + c];
                float4 v2 = h4[(size_t)(r2 & 0x1FFFFu) * 4 + c];
                float4 v3 = h4[(size_t)(r3 & 0x1FFFFu) * 4 + c];
                PROC(r0, v0); PROC(r1, v1); PROC(r2, v2); PROC(r3, v3);
            }
            for (; e < ge; ++e) {
                unsigned r0 = srcs[e];
                float4 v0 = h4[(size_t)(r0 & 0x1FFFFu) * 4 + c];
                PROC(r0, v0);
            }
            float* a = &acc[cur][c * 4];
            atomicAdd(a + 0, s.x); atomicAdd(a + 1, s.y);
            atomicAdd(a + 2, s.z); atomicAdd(a + 3, s.w);
        }
        __syncthreads();   // phase alignment across the block's waves
    }
#undef PROC
    int node = nfirst + g;
    if (node < n) {   // self contribution (unique 4 floats per thread)
        float4 self = h4[(size_t)node * 4 + c];
        float* ar = &acc[g][c * 4];
        ar[0] += self.x; ar[1] += self.y; ar[2] += self.z; ar[3] += self.w;
    }
    __syncthreads();
    if (node < n) {
        float di = dinv[node];
        float4 o = {0.f, 0.f, 0.f, 0.f};
        int j = c * 4;
#pragma unroll
        for (int k = 0; k < F; ++k) {
            float ak = acc[g][k];
            o.x += ak * Ws[k * F + j + 0];
            o.y += ak * Ws[k * F + j + 1];
            o.z += ak * Ws[k * F + j + 2];
            o.w += ak * Ws[k * F + j + 3];
        }
        float4 bi = ((const float4*)bias)[c];
        o.x = di * o.x + bi.x; o.y = di * o.y + bi.y;
        o.z = di * o.z + bi.z; o.w = di * o.w + bi.w;
        if (mode == 1) {
            o.x = fmaxf(o.x, 0.f) * di; o.y = fmaxf(o.y, 0.f) * di;
            o.z = fmaxf(o.z, 0.f) * di; o.w = fmaxf(o.w, 0.f) * di;
        }
        ((float4*)outp)[(size_t)node * 4 + c] = o;
    }
}

// ========================= fallback (R1) kernels ============================

__global__ void deg_kernel(const int* __restrict__ dst, float* __restrict__ deg, int E) {
    int e = blockIdx.x * blockDim.x + threadIdx.x;
    if (e < E) atomicAdd(&deg[dst[e]], 1.0f);
}
__global__ void dinv_kernel(float* __restrict__ deg, int n) {
    int i = blockIdx.x * blockDim.x + threadIdx.x;
    if (i < n) deg[i] = rsqrtf(deg[i] + 1.0f);
}
__global__ void linear2_kernel(const float* __restrict__ in, const float* __restrict__ acc,
                               const float* __restrict__ dinv, const float* __restrict__ W,
                               const float* __restrict__ bias, float* __restrict__ out,
                               int n, int mode) {
    __shared__ float Ws[F * F];
    __shared__ float As[16][F + 1];
    int t = threadIdx.x;
    Ws[t] = W[t];
    int nb = t >> 4, j = t & 15;
    int i = blockIdx.x * 16 + nb;
    float di = 0.f, v = 0.f;
    if (i < n) {
        di = dinv[i]; v = in[i * F + j];
        if (mode) { v = di * (acc[i * F + j] + v) + bias[j]; v = fmaxf(v, 0.f); }
    }
    As[nb][j] = v;
    __syncthreads();
    if (i < n) {
        float s = 0.f;
#pragma unroll
        for (int k = 0; k < F; ++k) s += As[nb][k] * Ws[k * F + j];
        out[i * F + j] = s * di;
    }
}
__global__ void scatter_kernel(const int* __restrict__ src, const int* __restrict__ dst,
                               const float* __restrict__ h, float* __restrict__ acc, int E) {
    int t = blockIdx.x * blockDim.x + threadIdx.x;
    int e = t >> 4, j = t & 15;
    if (e < E) atomicAdd(&acc[dst[e] * F + j], h[src[e] * F + j]);
}
__global__ void out_kernel(const float* __restrict__ acc, const float* __restrict__ h,
                           const float* __restrict__ dinv, const float* __restrict__ bias,
                           float* __restrict__ out, int n) {
    int t = blockIdx.x * blockDim.x + threadIdx.x;
    if (t < n * F) {
        int i = t >> 4, j = t & 15;
        out[t] = dinv[i] * (acc[t] + h[t]) + bias[j];
    }
}

// ========================= launch ===========================================

extern "C" void kernel_launch(void* const* d_in, const int* in_sizes, int n_in,
                              void* d_out, int out_size, void* d_ws, size_t ws_size,
                              hipStream_t stream) {
    const float* x  = (const float*)d_in[0];
    const int*   ei = (const int*)d_in[1];
    const float* W1 = (const float*)d_in[2];
    const float* b1 = (const float*)d_in[3];
    const float* W2 = (const float*)d_in[4];
    const float* b2 = (const float*)d_in[5];
    float* outp = (float*)d_out;

    const int N = in_sizes[0] / F;
    const int E = in_sizes[1] / 2;
    const int* src = ei;
    const int* dst = ei + E;

    const int nb_rt = (N + NPB - 1) >> BSHIFT;
    const size_t RC = (size_t)NB * BCAP;           // 3,603,456 entries (> 16N)
    // ws layout (4B units): dinv[N] | z[16N] | recs[RC] (y aliases) | srcs[RC] |
    //                       noffA[N] | nendA[N] | noffB[N] | nendB[N] | cursor[16*NB]
    size_t need = sizeof(unsigned) * ((size_t)N * 21 + 2 * RC + 16 * NB);

    if (nb_rt == NB && E <= CH * 65535 && ws_size >= need) {
        float* dinv = (float*)d_ws;
        float* z = dinv + N;
        unsigned* recs = (unsigned*)(z + (size_t)F * N);
        float* y = (float*)recs;                   // alias: recs dead after sort2
        unsigned* srcs = recs + RC;
        int* noffA = (int*)(srcs + RC);
        int* nendA = noffA + N;
        int* noffB = nendA + N;
        int* nendB = noffB + N;
        unsigned* cursor = (unsigned*)(nendB + N);

        init_cursor_kernel<<<1, 512, 0, stream>>>(cursor);
        reorder_kernel<<<(E + CH - 1) / CH, 512, 0, stream>>>(src, dst, cursor, recs, E);
        sort2_kernel<<<NB, 1024, 0, stream>>>(recs, cursor, srcs, noffA, nendA, noffB, nendB, dinv, x, z, N);
        agg_bal_kernel<<<(N + 63) / 64, 256, 0, stream>>>(z, srcs, noffA, nendA, noffB, nendB, dinv, W1, b1, y, N, 1);
        agg_bal_kernel<<<(N + 63) / 64, 256, 0, stream>>>(y, srcs, noffA, nendA, noffB, nendB, dinv, W2, b2, outp, N, 2);
    } else {
        // R1 fallback: atomic scatter path (13.2MB ws)
        float* dinv = (float*)d_ws;
        float* h = dinv + N;
        float* acc = h + (size_t)F * N;
        hipMemsetAsync(dinv, 0, (size_t)N * sizeof(float), stream);
        hipMemsetAsync(acc, 0, (size_t)F * N * sizeof(float), stream);
        deg_kernel<<<(E + 255) / 256, 256, 0, stream>>>(dst, dinv, E);
        dinv_kernel<<<(N + 255) / 256, 256, 0, stream>>>(dinv, N);
        linear2_kernel<<<(N + 15) / 16, 256, 0, stream>>>(x, nullptr, dinv, W1, nullptr, h, N, 0);
        scatter_kernel<<<((size_t)E * F + 255) / 256, 256, 0, stream>>>(src, dst, h, acc, E);
        linear2_kernel<<<(N + 15) / 16, 256, 0, stream>>>(h, acc, dinv, W2, b1, h, N, 1);
        hipMemsetAsync(acc, 0, (size_t)F * N * sizeof(float), stream);
        scatter_kernel<<<((size_t)E * F + 255) / 256, 256, 0, stream>>>(src, dst, h, acc, E);
        out_kernel<<<((size_t)N * F + 255) / 256, 256, 0, stream>>>(acc, h, dinv, b2, outp, N);
    }
}